// Round 1
// baseline (427.296 us; speedup 1.0000x reference)
//
#include <hip/hip_runtime.h>
#include <hip/hip_bf16.h>
#include <math.h>

#define DIM 8388608
#define EPS_F 1e-10f

// ws layout (floats):
// [0]=sum g^2, [1]=sum diff^2, [2]=sum g*diff, [3]=max|g| (float bits via uint atomicMax)
// [4..7]=s0..s3 (coeff_k * inv_norm), [8]=1/sqrt(1+it)

__global__ __launch_bounds__(256) void reduce_k(const float4* __restrict__ g4,
                                                const float4* __restrict__ a4,
                                                const float4* __restrict__ b4,
                                                float* __restrict__ red) {
    const int N4 = DIM / 4;
    int tid = blockIdx.x * blockDim.x + threadIdx.x;
    int stride = gridDim.x * blockDim.x;
    float ssg = 0.f, ssd = 0.f, sgd = 0.f, mx = 0.f;
    for (int i = tid; i < N4; i += stride) {
        float4 gv = g4[i], av = a4[i], bv = b4[i];
        float d0 = bv.x - av.x, d1 = bv.y - av.y, d2 = bv.z - av.z, d3 = bv.w - av.w;
        ssg = fmaf(gv.x, gv.x, ssg); ssg = fmaf(gv.y, gv.y, ssg);
        ssg = fmaf(gv.z, gv.z, ssg); ssg = fmaf(gv.w, gv.w, ssg);
        ssd = fmaf(d0, d0, ssd); ssd = fmaf(d1, d1, ssd);
        ssd = fmaf(d2, d2, ssd); ssd = fmaf(d3, d3, ssd);
        sgd = fmaf(gv.x, d0, sgd); sgd = fmaf(gv.y, d1, sgd);
        sgd = fmaf(gv.z, d2, sgd); sgd = fmaf(gv.w, d3, sgd);
        mx = fmaxf(mx, fabsf(gv.x)); mx = fmaxf(mx, fabsf(gv.y));
        mx = fmaxf(mx, fabsf(gv.z)); mx = fmaxf(mx, fabsf(gv.w));
    }
    // wave-64 reduce
    #pragma unroll
    for (int off = 32; off > 0; off >>= 1) {
        ssg += __shfl_down(ssg, off);
        ssd += __shfl_down(ssd, off);
        sgd += __shfl_down(sgd, off);
        mx = fmaxf(mx, __shfl_down(mx, off));
    }
    __shared__ float sm[4][4];
    int lane = threadIdx.x & 63, wid = threadIdx.x >> 6;
    if (lane == 0) { sm[wid][0] = ssg; sm[wid][1] = ssd; sm[wid][2] = sgd; sm[wid][3] = mx; }
    __syncthreads();
    if (threadIdx.x == 0) {
        float t0 = 0.f, t1 = 0.f, t2 = 0.f, t3 = 0.f;
        #pragma unroll
        for (int w = 0; w < 4; ++w) {
            t0 += sm[w][0]; t1 += sm[w][1]; t2 += sm[w][2]; t3 = fmaxf(t3, sm[w][3]);
        }
        atomicAdd(&red[0], t0);
        atomicAdd(&red[1], t1);
        atomicAdd(&red[2], t2);
        atomicMax((unsigned int*)&red[3], __float_as_uint(t3));
    }
}

__global__ __launch_bounds__(64) void mlp_k(const float* __restrict__ red,
                                            const float* __restrict__ loss_cur,
                                            const float* __restrict__ loss_old,
                                            const int* __restrict__ iter,
                                            const float* __restrict__ lw0, const float* __restrict__ lb0,
                                            const float* __restrict__ lw1, const float* __restrict__ lb1,
                                            const float* __restrict__ lw2, const float* __restrict__ lb2,
                                            const float* __restrict__ lw3, const float* __restrict__ lb3,
                                            float* __restrict__ ws) {
    __shared__ float buf[32];
    __shared__ float nxt[32];
    int t = threadIdx.x;
    float gn = sqrtf(red[0]);
    float dn = sqrtf(red[1]);
    float inv_gn = (gn > EPS_F) ? 1.f / gn : 1.f;
    float inv_dn = (dn > EPS_F) ? 1.f / dn : 1.f;
    float it = (float)iter[0];
    if (t < 6) {
        float f = 0.f;
        if (t == 0) f = log1pf(gn);
        else if (t == 1) f = log1pf(dn);
        else if (t == 2) f = red[2] * inv_gn * inv_dn;
        else if (t == 3) f = red[3] * inv_gn;   // red[3] bits are the nonneg float max|g|
        else if (t == 4) f = it;
        else f = logf(loss_cur[0]) - logf(loss_old[0]);
        buf[t] = f;
    }
    __syncthreads();
    // layer0: 6 -> 30, relu   (reads buf, writes nxt)
    float acc = 0.f;
    if (t < 30) {
        acc = lb0[t];
        #pragma unroll
        for (int c = 0; c < 6; ++c) acc = fmaf(lw0[t * 6 + c], buf[c], acc);
        acc = fmaxf(acc, 0.f);
        nxt[t] = acc;
    }
    __syncthreads();
    // layer1: 30 -> 20, relu  (reads nxt, writes buf)
    if (t < 20) {
        acc = lb1[t];
        #pragma unroll
        for (int c = 0; c < 30; ++c) acc = fmaf(lw1[t * 30 + c], nxt[c], acc);
        acc = fmaxf(acc, 0.f);
        buf[t] = acc;
    }
    __syncthreads();
    // layer2: 20 -> 10, relu  (reads buf, writes nxt)
    if (t < 10) {
        acc = lb2[t];
        #pragma unroll
        for (int c = 0; c < 20; ++c) acc = fmaf(lw2[t * 20 + c], buf[c], acc);
        acc = fmaxf(acc, 0.f);
        nxt[t] = acc;
    }
    __syncthreads();
    // layer3: 10 -> 4 (no relu); fuse with inv-norms
    if (t < 4) {
        acc = lb3[t];
        #pragma unroll
        for (int c = 0; c < 10; ++c) acc = fmaf(lw3[t * 10 + c], nxt[c], acc);
        float s = ((t & 1) == 0) ? acc * inv_gn : acc * inv_dn;  // t=0,2 -> g path; t=1,3 -> d path
        ws[4 + t] = s;
    }
    if (t == 0) ws[8] = rsqrtf(1.f + it);
}

__global__ __launch_bounds__(256) void apply_k(const float4* __restrict__ g4,
                                               const float4* __restrict__ a4,
                                               const float4* __restrict__ b4,
                                               const float4* __restrict__ gp4,
                                               const float4* __restrict__ ex4,
                                               const float* __restrict__ cw0, const float* __restrict__ cb0,
                                               const float* __restrict__ cw1, const float* __restrict__ cb1,
                                               const float* __restrict__ cw2, const float* __restrict__ cb2,
                                               const float* __restrict__ cw3, const float* __restrict__ cb3,
                                               const float* __restrict__ ws,
                                               float4* __restrict__ out4) {
    __shared__ float sw[964];
    int t = threadIdx.x;
    for (int i = t; i < 80;  i += 256) sw[i]        = cw0[i];
    for (int i = t; i < 20;  i += 256) sw[80 + i]   = cb0[i];
    for (int i = t; i < 400; i += 256) sw[100 + i]  = cw1[i];
    for (int i = t; i < 20;  i += 256) sw[500 + i]  = cb1[i];
    for (int i = t; i < 400; i += 256) sw[520 + i]  = cw2[i];
    for (int i = t; i < 20;  i += 256) sw[920 + i]  = cb2[i];
    for (int i = t; i < 20;  i += 256) sw[940 + i]  = cw3[i];
    if (t == 0) sw[960] = cb3[0];
    float s0 = ws[4], s1 = ws[5], s2 = ws[6], s3 = ws[7], isq = ws[8];
    __syncthreads();
    const float* W0 = sw;        const float* B0 = sw + 80;
    const float* W1 = sw + 100;  const float* B1 = sw + 500;
    const float* W2 = sw + 520;  const float* B2 = sw + 920;
    const float* W3 = sw + 940;  const float  B3v = sw[960];

    int i = blockIdx.x * blockDim.x + threadIdx.x;   // exactly DIM/4 threads
    float4 gv = g4[i], av = a4[i], bv = b4[i], pv = gp4[i], ev = ex4[i];
    float gg[4] = {gv.x, gv.y, gv.z, gv.w};
    float aa[4] = {av.x, av.y, av.z, av.w};
    float st[4] = {bv.x, bv.y, bv.z, bv.w};
    float pp[4] = {pv.x, pv.y, pv.z, pv.w};
    float ee[4] = {ev.x, ev.y, ev.z, ev.w};

    float x[4][4];
    #pragma unroll
    for (int e = 0; e < 4; ++e) {
        float ge = gg[e];
        float de = st[e] - aa[e];
        x[e][0] = s0 * pp[e] * ge;
        x[e][1] = s1 * ee[e] * de;
        x[e][2] = s2 * ge;
        x[e][3] = s3 * de;
    }

    float h[4][20], h2[4][20];
    // layer0: 4 -> 20, relu
    #pragma unroll
    for (int o = 0; o < 20; ++o) {
        float b = B0[o];
        float c0 = b, c1 = b, c2 = b, c3 = b;
        #pragma unroll
        for (int c = 0; c < 4; ++c) {
            float wv = W0[o * 4 + c];
            c0 = fmaf(wv, x[0][c], c0);
            c1 = fmaf(wv, x[1][c], c1);
            c2 = fmaf(wv, x[2][c], c2);
            c3 = fmaf(wv, x[3][c], c3);
        }
        h[0][o] = fmaxf(c0, 0.f); h[1][o] = fmaxf(c1, 0.f);
        h[2][o] = fmaxf(c2, 0.f); h[3][o] = fmaxf(c3, 0.f);
    }
    // layer1: 20 -> 20, relu
    #pragma unroll
    for (int o = 0; o < 20; ++o) {
        float b = B1[o];
        float c0 = b, c1 = b, c2 = b, c3 = b;
        #pragma unroll
        for (int c = 0; c < 20; ++c) {
            float wv = W1[o * 20 + c];
            c0 = fmaf(wv, h[0][c], c0);
            c1 = fmaf(wv, h[1][c], c1);
            c2 = fmaf(wv, h[2][c], c2);
            c3 = fmaf(wv, h[3][c], c3);
        }
        h2[0][o] = fmaxf(c0, 0.f); h2[1][o] = fmaxf(c1, 0.f);
        h2[2][o] = fmaxf(c2, 0.f); h2[3][o] = fmaxf(c3, 0.f);
    }
    // layer2: 20 -> 20, relu
    #pragma unroll
    for (int o = 0; o < 20; ++o) {
        float b = B2[o];
        float c0 = b, c1 = b, c2 = b, c3 = b;
        #pragma unroll
        for (int c = 0; c < 20; ++c) {
            float wv = W2[o * 20 + c];
            c0 = fmaf(wv, h2[0][c], c0);
            c1 = fmaf(wv, h2[1][c], c1);
            c2 = fmaf(wv, h2[2][c], c2);
            c3 = fmaf(wv, h2[3][c], c3);
        }
        h[0][o] = fmaxf(c0, 0.f); h[1][o] = fmaxf(c1, 0.f);
        h[2][o] = fmaxf(c2, 0.f); h[3][o] = fmaxf(c3, 0.f);
    }
    // layer3: 20 -> 1 (no relu), fuse epilogue
    float d0 = B3v, d1 = B3v, d2 = B3v, d3 = B3v;
    #pragma unroll
    for (int c = 0; c < 20; ++c) {
        float wv = W3[c];
        d0 = fmaf(wv, h[0][c], d0);
        d1 = fmaf(wv, h[1][c], d1);
        d2 = fmaf(wv, h[2][c], d2);
        d3 = fmaf(wv, h[3][c], d3);
    }
    float4 outv;
    outv.x = fmaf(d0, isq, st[0]);
    outv.y = fmaf(d1, isq, st[1]);
    outv.z = fmaf(d2, isq, st[2]);
    outv.w = fmaf(d3, isq, st[3]);
    out4[i] = outv;
}

extern "C" void kernel_launch(void* const* d_in, const int* in_sizes, int n_in,
                              void* d_out, int out_size, void* d_ws, size_t ws_size,
                              hipStream_t stream) {
    const float* grad    = (const float*)d_in[0];
    const float* state0  = (const float*)d_in[1];
    const float* state1  = (const float*)d_in[2];
    const float* losscur = (const float*)d_in[3];
    const float* lossold = (const float*)d_in[4];
    const int*   iter    = (const int*)d_in[5];
    const float* gparam  = (const float*)d_in[6];
    const float* extrap  = (const float*)d_in[7];
    const float* cw0 = (const float*)d_in[8];  const float* cb0 = (const float*)d_in[9];
    const float* cw1 = (const float*)d_in[10]; const float* cb1 = (const float*)d_in[11];
    const float* cw2 = (const float*)d_in[12]; const float* cb2 = (const float*)d_in[13];
    const float* cw3 = (const float*)d_in[14]; const float* cb3 = (const float*)d_in[15];
    const float* lw0 = (const float*)d_in[16]; const float* lb0 = (const float*)d_in[17];
    const float* lw1 = (const float*)d_in[18]; const float* lb1 = (const float*)d_in[19];
    const float* lw2 = (const float*)d_in[20]; const float* lb2 = (const float*)d_in[21];
    const float* lw3 = (const float*)d_in[22]; const float* lb3 = (const float*)d_in[23];

    float* ws = (float*)d_ws;
    float* out = (float*)d_out;

    hipMemsetAsync(d_ws, 0, 256, stream);

    reduce_k<<<1024, 256, 0, stream>>>((const float4*)grad, (const float4*)state0,
                                       (const float4*)state1, ws);

    mlp_k<<<1, 64, 0, stream>>>(ws, losscur, lossold, iter,
                                lw0, lb0, lw1, lb1, lw2, lb2, lw3, lb3, ws);

    apply_k<<<DIM / 4 / 256, 256, 0, stream>>>((const float4*)grad, (const float4*)state0,
                                               (const float4*)state1, (const float4*)gparam,
                                               (const float4*)extrap,
                                               cw0, cb0, cw1, cb1, cw2, cb2, cw3, cb3,
                                               ws, (float4*)out);
}

// Round 3
// 329.491 us; speedup vs baseline: 1.2968x; 1.2968x over previous
//
#include <hip/hip_runtime.h>
#include <math.h>

#define DIM 8388608
#define NBLK_RED 1024
#define EPS_F 1e-10f

typedef _Float16 h2 __attribute__((ext_vector_type(2)));

// ws layout (floats):
// [0 .. 4096)    per-block reduction partials: float4 per block {sum g^2, sum d^2, sum g*d, max|g|}
// [4096..4101)   s0, s1, s2, s3 (coeff_k * inv_norm), isq = 1/sqrt(1+it)
// [4104..5065)   h2 (w,w) conv weights/biases:
//                W0[80] B0[20] W1[400] B1[20] W2[400] B2[20] W3[20] B3[1]
#define WS_SCAL 4096
#define WS_WH   4104

__global__ __launch_bounds__(256) void reduce_k(const float4* __restrict__ g4,
                                                const float4* __restrict__ a4,
                                                const float4* __restrict__ b4,
                                                float4* __restrict__ part4) {
    const int N4 = DIM / 4;
    int tid = blockIdx.x * blockDim.x + threadIdx.x;
    int stride = gridDim.x * blockDim.x;
    float ssg = 0.f, ssd = 0.f, sgd = 0.f, mx = 0.f;
    for (int i = tid; i < N4; i += stride) {
        float4 gv = g4[i], av = a4[i], bv = b4[i];
        float d0 = bv.x - av.x, d1 = bv.y - av.y, d2 = bv.z - av.z, d3 = bv.w - av.w;
        ssg = fmaf(gv.x, gv.x, ssg); ssg = fmaf(gv.y, gv.y, ssg);
        ssg = fmaf(gv.z, gv.z, ssg); ssg = fmaf(gv.w, gv.w, ssg);
        ssd = fmaf(d0, d0, ssd); ssd = fmaf(d1, d1, ssd);
        ssd = fmaf(d2, d2, ssd); ssd = fmaf(d3, d3, ssd);
        sgd = fmaf(gv.x, d0, sgd); sgd = fmaf(gv.y, d1, sgd);
        sgd = fmaf(gv.z, d2, sgd); sgd = fmaf(gv.w, d3, sgd);
        mx = fmaxf(mx, fabsf(gv.x)); mx = fmaxf(mx, fabsf(gv.y));
        mx = fmaxf(mx, fabsf(gv.z)); mx = fmaxf(mx, fabsf(gv.w));
    }
    #pragma unroll
    for (int off = 32; off > 0; off >>= 1) {
        ssg += __shfl_down(ssg, off);
        ssd += __shfl_down(ssd, off);
        sgd += __shfl_down(sgd, off);
        mx = fmaxf(mx, __shfl_down(mx, off));
    }
    __shared__ float sm[4][4];
    int lane = threadIdx.x & 63, wid = threadIdx.x >> 6;
    if (lane == 0) { sm[wid][0] = ssg; sm[wid][1] = ssd; sm[wid][2] = sgd; sm[wid][3] = mx; }
    __syncthreads();
    if (threadIdx.x == 0) {
        float t0 = 0.f, t1 = 0.f, t2 = 0.f, t3 = 0.f;
        #pragma unroll
        for (int w = 0; w < 4; ++w) {
            t0 += sm[w][0]; t1 += sm[w][1]; t2 += sm[w][2]; t3 = fmaxf(t3, sm[w][3]);
        }
        part4[blockIdx.x] = make_float4(t0, t1, t2, t3);
    }
}

__global__ __launch_bounds__(64) void mlp_k(float* __restrict__ wsf,
                                            const float* __restrict__ loss_cur,
                                            const float* __restrict__ loss_old,
                                            const int* __restrict__ iter,
                                            const float* __restrict__ lw0, const float* __restrict__ lb0,
                                            const float* __restrict__ lw1, const float* __restrict__ lb1,
                                            const float* __restrict__ lw2, const float* __restrict__ lb2,
                                            const float* __restrict__ lw3, const float* __restrict__ lb3,
                                            const float* __restrict__ cw0, const float* __restrict__ cb0,
                                            const float* __restrict__ cw1, const float* __restrict__ cb1,
                                            const float* __restrict__ cw2, const float* __restrict__ cb2,
                                            const float* __restrict__ cw3, const float* __restrict__ cb3) {
    int t = threadIdx.x;

    // --- convert conv weights to (w,w) packed-half pairs in ws ---
    h2* wh = (h2*)(wsf + WS_WH);
    for (int i = t; i < 80;  i += 64) { _Float16 w = (_Float16)cw0[i]; wh[i]       = (h2){w, w}; }
    for (int i = t; i < 20;  i += 64) { _Float16 w = (_Float16)cb0[i]; wh[80 + i]  = (h2){w, w}; }
    for (int i = t; i < 400; i += 64) { _Float16 w = (_Float16)cw1[i]; wh[100 + i] = (h2){w, w}; }
    for (int i = t; i < 20;  i += 64) { _Float16 w = (_Float16)cb1[i]; wh[500 + i] = (h2){w, w}; }
    for (int i = t; i < 400; i += 64) { _Float16 w = (_Float16)cw2[i]; wh[520 + i] = (h2){w, w}; }
    for (int i = t; i < 20;  i += 64) { _Float16 w = (_Float16)cb2[i]; wh[920 + i] = (h2){w, w}; }
    for (int i = t; i < 20;  i += 64) { _Float16 w = (_Float16)cw3[i]; wh[940 + i] = (h2){w, w}; }
    if (t == 0) { _Float16 w = (_Float16)cb3[0]; wh[960] = (h2){w, w}; }

    // --- final reduction over per-block partials ---
    const float4* part4 = (const float4*)wsf;
    float ssg = 0.f, ssd = 0.f, sgd = 0.f, mx = 0.f;
    for (int b = t; b < NBLK_RED; b += 64) {
        float4 p = part4[b];
        ssg += p.x; ssd += p.y; sgd += p.z; mx = fmaxf(mx, p.w);
    }
    #pragma unroll
    for (int off = 32; off > 0; off >>= 1) {
        ssg += __shfl_down(ssg, off);
        ssd += __shfl_down(ssd, off);
        sgd += __shfl_down(sgd, off);
        mx = fmaxf(mx, __shfl_down(mx, off));
    }
    __shared__ float red[4];
    if (t == 0) { red[0] = ssg; red[1] = ssd; red[2] = sgd; red[3] = mx; }
    __syncthreads();

    __shared__ float buf[32];
    __shared__ float nxt[32];
    float gn = sqrtf(red[0]);
    float dn = sqrtf(red[1]);
    float inv_gn = (gn > EPS_F) ? 1.f / gn : 1.f;
    float inv_dn = (dn > EPS_F) ? 1.f / dn : 1.f;
    float it = (float)iter[0];
    if (t < 6) {
        float f = 0.f;
        if (t == 0) f = log1pf(gn);
        else if (t == 1) f = log1pf(dn);
        else if (t == 2) f = red[2] * inv_gn * inv_dn;
        else if (t == 3) f = red[3] * inv_gn;
        else if (t == 4) f = it;
        else f = logf(loss_cur[0]) - logf(loss_old[0]);
        buf[t] = f;
    }
    __syncthreads();
    float acc;
    if (t < 30) {
        acc = lb0[t];
        #pragma unroll
        for (int c = 0; c < 6; ++c) acc = fmaf(lw0[t * 6 + c], buf[c], acc);
        nxt[t] = fmaxf(acc, 0.f);
    }
    __syncthreads();
    if (t < 20) {
        acc = lb1[t];
        #pragma unroll
        for (int c = 0; c < 30; ++c) acc = fmaf(lw1[t * 30 + c], nxt[c], acc);
        buf[t] = fmaxf(acc, 0.f);
    }
    __syncthreads();
    if (t < 10) {
        acc = lb2[t];
        #pragma unroll
        for (int c = 0; c < 20; ++c) acc = fmaf(lw2[t * 20 + c], buf[c], acc);
        nxt[t] = fmaxf(acc, 0.f);
    }
    __syncthreads();
    if (t < 4) {
        acc = lb3[t];
        #pragma unroll
        for (int c = 0; c < 10; ++c) acc = fmaf(lw3[t * 10 + c], nxt[c], acc);
        float s = ((t & 1) == 0) ? acc * inv_gn : acc * inv_dn;  // t=0,2 g-path; t=1,3 d-path
        wsf[WS_SCAL + t] = s;
    }
    if (t == 0) wsf[WS_SCAL + 4] = rsqrtf(1.f + it);
}

__global__ __launch_bounds__(256) void apply_k(const float4* __restrict__ g4,
                                               const float4* __restrict__ a4,
                                               const float4* __restrict__ b4,
                                               const float4* __restrict__ gp4,
                                               const float4* __restrict__ ex4,
                                               const float* __restrict__ wsf,
                                               float4* __restrict__ out4) {
    // uniform scalars (scalar loads)
    float s0 = wsf[WS_SCAL + 0], s1 = wsf[WS_SCAL + 1];
    float s2 = wsf[WS_SCAL + 2], s3 = wsf[WS_SCAL + 3];
    float isq = wsf[WS_SCAL + 4];
    const h2* __restrict__ wh = (const h2*)(wsf + WS_WH);
    const h2* W0 = wh;        const h2* B0 = wh + 80;
    const h2* W1 = wh + 100;  const h2* B1 = wh + 500;
    const h2* W2 = wh + 520;  const h2* B2 = wh + 920;
    const h2* W3 = wh + 940;  const h2  B3v = wh[960];

    int i = blockIdx.x * blockDim.x + threadIdx.x;   // exactly DIM/4 threads
    float4 gv = g4[i], av = a4[i], bv = b4[i], pv = gp4[i], ev = ex4[i];
    float st[4] = {bv.x, bv.y, bv.z, bv.w};
    float de[4] = {bv.x - av.x, bv.y - av.y, bv.z - av.z, bv.w - av.w};
    float gg[4] = {gv.x, gv.y, gv.z, gv.w};
    float pp[4] = {pv.x, pv.y, pv.z, pv.w};
    float ee[4] = {ev.x, ev.y, ev.z, ev.w};

    // x channels as packed pairs: pair p covers elements {2p, 2p+1}
    h2 xh[2][4];
    #pragma unroll
    for (int p = 0; p < 2; ++p) {
        int e0 = 2 * p, e1 = 2 * p + 1;
        xh[p][0] = (h2){(_Float16)(s0 * pp[e0] * gg[e0]), (_Float16)(s0 * pp[e1] * gg[e1])};
        xh[p][1] = (h2){(_Float16)(s1 * ee[e0] * de[e0]), (_Float16)(s1 * ee[e1] * de[e1])};
        xh[p][2] = (h2){(_Float16)(s2 * gg[e0]), (_Float16)(s2 * gg[e1])};
        xh[p][3] = (h2){(_Float16)(s3 * de[e0]), (_Float16)(s3 * de[e1])};
    }

    const h2 zero = (h2){(_Float16)0.f, (_Float16)0.f};
    h2 h[2][20], hb[2][20];
    // layer0: 4 -> 20, relu
    #pragma unroll
    for (int o = 0; o < 20; ++o) {
        h2 b = B0[o];
        h2 c0 = b, c1 = b;
        #pragma unroll
        for (int c = 0; c < 4; ++c) {
            h2 wv = W0[o * 4 + c];
            c0 = wv * xh[0][c] + c0;
            c1 = wv * xh[1][c] + c1;
        }
        h[0][o] = __builtin_elementwise_max(c0, zero);
        h[1][o] = __builtin_elementwise_max(c1, zero);
    }
    // layer1: 20 -> 20, relu
    #pragma unroll
    for (int o = 0; o < 20; ++o) {
        h2 b = B1[o];
        h2 c0 = b, c1 = b;
        #pragma unroll
        for (int c = 0; c < 20; ++c) {
            h2 wv = W1[o * 20 + c];
            c0 = wv * h[0][c] + c0;
            c1 = wv * h[1][c] + c1;
        }
        hb[0][o] = __builtin_elementwise_max(c0, zero);
        hb[1][o] = __builtin_elementwise_max(c1, zero);
    }
    // layer2: 20 -> 20, relu
    #pragma unroll
    for (int o = 0; o < 20; ++o) {
        h2 b = B2[o];
        h2 c0 = b, c1 = b;
        #pragma unroll
        for (int c = 0; c < 20; ++c) {
            h2 wv = W2[o * 20 + c];
            c0 = wv * hb[0][c] + c0;
            c1 = wv * hb[1][c] + c1;
        }
        h[0][o] = __builtin_elementwise_max(c0, zero);
        h[1][o] = __builtin_elementwise_max(c1, zero);
    }
    // layer3: 20 -> 1 (no relu)
    h2 d0 = B3v, d1 = B3v;
    #pragma unroll
    for (int c = 0; c < 20; ++c) {
        h2 wv = W3[c];
        d0 = wv * h[0][c] + d0;
        d1 = wv * h[1][c] + d1;
    }
    float4 outv;
    outv.x = fmaf((float)d0[0], isq, st[0]);
    outv.y = fmaf((float)d0[1], isq, st[1]);
    outv.z = fmaf((float)d1[0], isq, st[2]);
    outv.w = fmaf((float)d1[1], isq, st[3]);
    out4[i] = outv;
}

extern "C" void kernel_launch(void* const* d_in, const int* in_sizes, int n_in,
                              void* d_out, int out_size, void* d_ws, size_t ws_size,
                              hipStream_t stream) {
    const float* grad    = (const float*)d_in[0];
    const float* state0  = (const float*)d_in[1];
    const float* state1  = (const float*)d_in[2];
    const float* losscur = (const float*)d_in[3];
    const float* lossold = (const float*)d_in[4];
    const int*   iter    = (const int*)d_in[5];
    const float* gparam  = (const float*)d_in[6];
    const float* extrap  = (const float*)d_in[7];
    const float* cw0 = (const float*)d_in[8];  const float* cb0 = (const float*)d_in[9];
    const float* cw1 = (const float*)d_in[10]; const float* cb1 = (const float*)d_in[11];
    const float* cw2 = (const float*)d_in[12]; const float* cb2 = (const float*)d_in[13];
    const float* cw3 = (const float*)d_in[14]; const float* cb3 = (const float*)d_in[15];
    const float* lw0 = (const float*)d_in[16]; const float* lb0 = (const float*)d_in[17];
    const float* lw1 = (const float*)d_in[18]; const float* lb1 = (const float*)d_in[19];
    const float* lw2 = (const float*)d_in[20]; const float* lb2 = (const float*)d_in[21];
    const float* lw3 = (const float*)d_in[22]; const float* lb3 = (const float*)d_in[23];

    float* wsf = (float*)d_ws;
    float* out = (float*)d_out;

    reduce_k<<<NBLK_RED, 256, 0, stream>>>((const float4*)grad, (const float4*)state0,
                                           (const float4*)state1, (float4*)wsf);

    mlp_k<<<1, 64, 0, stream>>>(wsf, losscur, lossold, iter,
                                lw0, lb0, lw1, lb1, lw2, lb2, lw3, lb3,
                                cw0, cb0, cw1, cb1, cw2, cb2, cw3, cb3);

    apply_k<<<DIM / 4 / 256, 256, 0, stream>>>((const float4*)grad, (const float4*)state0,
                                               (const float4*)state1, (const float4*)gparam,
                                               (const float4*)extrap,
                                               wsf, (float4*)out);
}